// Round 6
// baseline (135.547 us; speedup 1.0000x reference)
//
#include <hip/hip_runtime.h>

typedef __attribute__((ext_vector_type(8))) short bf16x8;
typedef __attribute__((ext_vector_type(16))) float f32x16;

namespace {
constexpr int Bn = 8, Cn = 256, Hn = 96, Wn = 128;
constexpr int HWn = Hn * Wn;     // 12288
constexpr int KC = 32;           // channels per staged chunk
constexpr int SP = 40;           // LDS pitch (bf16) per (row,wi): 80B -> b128 reads conflict-free
constexpr int SW = 72;           // staged second width  (w' = wb-4 .. wb+67)
constexpr int SR = 6;            // staged second rows (4h + 3dy window -> 6)
constexpr int FW = 64;           // first width per block (w-half)
constexpr int SSZ = SR * SW * SP;            // 17280 ushort
constexpr int FSZ = (4 * FW + 8) * SP;       // 10560 ushort (+8 wl pad for A-frag overread)
constexpr int BUF = SSZ + FSZ;               // 27840 ushort = 55680 B per buffer
constexpr int NBLK = 8 * 24 * 2 * 3;         // 1152 blocks (b, hq, wh, dg)
}

// round-to-nearest-even fp32 -> bf16, packed pair
__device__ __forceinline__ unsigned f2bfpk(float lo, float hi) {
  unsigned a = __float_as_uint(lo), b = __float_as_uint(hi);
  a = ((a + 0x7FFF + ((a >> 16) & 1)) >> 16) & 0xFFFF;
  b = ((b + 0x7FFF + ((b >> 16) & 1)) >> 16) & 0xFFFF;
  return (b << 16) | a;
}

__global__ __launch_bounds__(768, 1) void corr_mfma(
    const float* __restrict__ first, const float* __restrict__ second,
    float* __restrict__ out)
{
  __shared__ __align__(16) unsigned short LB[2][BUF];  // 111,360 B

  const int tid = threadIdx.x;
  const int wv = tid >> 6;         // 0..11
  const int lane = tid & 63;
  const int ln31 = lane & 31;      // MFMA m / n index
  const int half = lane >> 5;      // MFMA k-block
  const int li4 = lane >> 2;       // staging: wi sub-index
  const int lm4 = lane & 3;        // staging: c sub-index

  // block decode with XCD swizzle (batch image b stays on one XCD's L2)
  const int bid = blockIdx.x;
  const int logical = (bid & 7) * (NBLK / 8) + (bid >> 3);
  const int b = logical / 144;
  int rest = logical % 144;
  const int hq = rest / 6; rest %= 6;
  const int wh = rest / 3;
  const int dg = rest % 3;                   // dy group: dy = 3*dg + dd
  const int h0 = hq * 4, wb = wh * 64;
  const int rbase = h0 + dg * 3 - 4;         // first staged second-row

  // wave -> (h row, w tile)
  const int hh = wv / 3;                     // 0..3
  const int tt = wv % 3;
  const int toff = (tt == 0) ? 0 : (tt == 1) ? 24 : 40;  // tile covers m 0..23

  f32x16 acc0 = {}, acc1 = {}, acc2 = {};

  float sx[16][2];  // staged loads in flight (constant-indexed -> registers)

  // ---- staging: LOADS(ck) fills sx; WRITES(ck,buf) packs to LDS ----
  auto LOADS = [&](int ck) {
#pragma unroll
    for (int st = 0; st < 8; ++st) {         // S full-width tasks
      const int id = wv * 8 + st;            // 0..95
      const int r = id >> 4, q = id & 15;
      const int cl = ((q >> 2) << 3) + (lm4 << 1);
      const int wi = ((q & 3) << 4) + li4;
      const int rg = rbase + r, wg = wb - 4 + wi;
      const int rgc = min(Hn - 1, max(0, rg));
      const int wgc = min(Wn - 1, max(0, wg));
      const bool v = (rg >= 0) & (rg < Hn) & (wg >= 0) & (wg < Wn);
      const float* p = second + ((b * Cn + ck + cl) * Hn + rgc) * Wn + wgc;
      sx[st][0] = v ? p[0] : 0.0f;
      sx[st][1] = v ? p[HWn] : 0.0f;
    }
#pragma unroll
    for (int pt = 0; pt < 2; ++pt) {         // S partial (wi 64..71), lanes<32 useful
      const int id = wv * 2 + pt;            // 0..23
      const int r = id >> 2, cbi = id & 3;
      const int cl = (cbi << 3) + (lm4 << 1);
      const int wi = 64 + li4;
      const int rg = rbase + r, wg = wb - 4 + wi;
      const int rgc = min(Hn - 1, max(0, rg));
      const int wgc = min(Wn - 1, max(0, wg));
      const bool v = (lane < 32) & (rg >= 0) & (rg < Hn) & (wg >= 0) & (wg < Wn);
      const float* p = second + ((b * Cn + ck + cl) * Hn + rgc) * Wn + wgc;
      sx[8 + pt][0] = v ? p[0] : 0.0f;
      sx[8 + pt][1] = v ? p[HWn] : 0.0f;
    }
#pragma unroll
    for (int k = 0; k < 6; ++k) {            // F tasks
      const int ft = wv + 12 * k;            // 0..107, valid < 64
      if (ft < 64) {
        const int hh2 = ft >> 4, q = ft & 15;
        const int cl = ((q >> 2) << 3) + (lm4 << 1);
        const int wl = ((q & 3) << 4) + li4;
        const float* p = first + ((b * Cn + ck + cl) * Hn + h0 + hh2) * Wn + wb + wl;
        sx[10 + k][0] = p[0];
        sx[10 + k][1] = p[HWn];
      }
    }
  };

  auto WRITES = [&](unsigned short* lb) {
#pragma unroll
    for (int st = 0; st < 8; ++st) {
      const int id = wv * 8 + st;
      const int r = id >> 4, q = id & 15;
      const int cl = ((q >> 2) << 3) + (lm4 << 1);
      const int wi = ((q & 3) << 4) + li4;
      *(unsigned*)&lb[(r * SW + wi) * SP + cl] = f2bfpk(sx[st][0], sx[st][1]);
    }
#pragma unroll
    for (int pt = 0; pt < 2; ++pt) {
      const int id = wv * 2 + pt;
      const int r = id >> 2, cbi = id & 3;
      const int cl = (cbi << 3) + (lm4 << 1);
      const int wi = 64 + li4;
      if (lane < 32)
        *(unsigned*)&lb[(r * SW + wi) * SP + cl] = f2bfpk(sx[8 + pt][0], sx[8 + pt][1]);
    }
#pragma unroll
    for (int k = 0; k < 6; ++k) {
      const int ft = wv + 12 * k;
      if (ft < 64) {
        const int hh2 = ft >> 4, q = ft & 15;
        const int cl = ((q >> 2) << 3) + (lm4 << 1);
        const int wl = ((q & 3) << 4) + li4;
        *(unsigned*)&lb[SSZ + (hh2 * FW + wl) * SP + cl] = f2bfpk(sx[10 + k][0], sx[10 + k][1]);
      }
    }
  };

  auto COMPUTE = [&](const unsigned short* sb) {
    const unsigned short* fb = sb + SSZ;
    const int abase = (hh * FW + toff + ln31) * SP + (half << 3);
    bf16x8 a0 = *(const bf16x8*)(fb + abase);
    bf16x8 a1 = *(const bf16x8*)(fb + abase + 16);
    const int b0 = ((hh + 0) * SW + toff + ln31) * SP + (half << 3);
    const int b1 = b0 + SW * SP;
    const int b2 = b1 + SW * SP;
    bf16x8 s00 = *(const bf16x8*)(sb + b0);
    bf16x8 s01 = *(const bf16x8*)(sb + b0 + 16);
    bf16x8 s10 = *(const bf16x8*)(sb + b1);
    bf16x8 s11 = *(const bf16x8*)(sb + b1 + 16);
    bf16x8 s20 = *(const bf16x8*)(sb + b2);
    bf16x8 s21 = *(const bf16x8*)(sb + b2 + 16);
    acc0 = __builtin_amdgcn_mfma_f32_32x32x16_bf16(a0, s00, acc0, 0, 0, 0);
    acc0 = __builtin_amdgcn_mfma_f32_32x32x16_bf16(a1, s01, acc0, 0, 0, 0);
    acc1 = __builtin_amdgcn_mfma_f32_32x32x16_bf16(a0, s10, acc1, 0, 0, 0);
    acc1 = __builtin_amdgcn_mfma_f32_32x32x16_bf16(a1, s11, acc1, 0, 0, 0);
    acc2 = __builtin_amdgcn_mfma_f32_32x32x16_bf16(a0, s20, acc2, 0, 0, 0);
    acc2 = __builtin_amdgcn_mfma_f32_32x32x16_bf16(a1, s21, acc2, 0, 0, 0);
  };

  // prologue: stage chunk 0
  LOADS(0);
  WRITES(&LB[0][0]);
  __syncthreads();

#pragma unroll 2
  for (int k = 0; k < 8; ++k) {
    if (k < 7) LOADS((k + 1) * KC);          // issue next-chunk loads early (T14)
    COMPUTE(&LB[k & 1][0]);                  // MFMA hides global-load latency
    if (k < 7) WRITES(&LB[(k + 1) & 1][0]);  // pack+write after compute
    __syncthreads();
  }

  // ---- epilogue: acc -> LDS transpose -> coalesced stores ----
  float* outl = (float*)&LB[0][0];           // [4h][64w][29ch-pitch] = 29,696 B
  const float sc = 1.0f / 256.0f;
#pragma unroll
  for (int dd = 0; dd < 3; ++dd) {
    const f32x16& A = (dd == 0) ? acc0 : (dd == 1) ? acc1 : acc2;
#pragma unroll
    for (int q = 0; q < 16; ++q) {
      const int m = (q & 3) + ((q >> 2) << 3) + (half << 2);  // verified C/D row map
      const int dxi = ln31 - m;                               // dx channel index
      if (m < 24 && dxi >= 0 && dxi <= 8)
        outl[(hh * FW + toff + m) * 29 + dd * 9 + dxi] = A[q] * sc;
    }
  }
  __syncthreads();
#pragma unroll
  for (int k2 = 0; k2 < 9; ++k2) {
    const int sp = wv + 12 * k2;             // 0..107 = 27ch x 4h
    const int ch = sp % 27, hh2 = sp / 27;
    out[((b * 81 + dg * 27 + ch) * Hn + h0 + hh2) * Wn + wb + lane] =
        outl[(hh2 * FW + lane) * 29 + ch];
  }
}

extern "C" void kernel_launch(void* const* d_in, const int* in_sizes, int n_in,
                              void* d_out, int out_size, void* d_ws, size_t ws_size,
                              hipStream_t stream) {
  const float* first = (const float*)d_in[0];
  const float* second = (const float*)d_in[1];
  float* out = (float*)d_out;
  corr_mfma<<<dim3(NBLK), dim3(768), 0, stream>>>(first, second, out);
}